// Round 5
// baseline (1310.419 us; speedup 1.0000x reference)
//
#include <hip/hip_runtime.h>
#include <hip/hip_fp16.h>
#include <stdint.h>
#include <cmath>

static constexpr int NUM_LEVELS = 16;
static constexpr uint32_t HASH_SIZE = 1u << 19;
static constexpr uint32_t HMASK = HASH_SIZE - 1u;

typedef float f2_t __attribute__((ext_vector_type(2)));
typedef float f4_t __attribute__((ext_vector_type(4)));

struct ResArr { float r[NUM_LEVELS]; };

// L1-bypass gather: agent-scope relaxed load -> global_load_dword ... sc0
// (read-through to L2; avoids the per-CU L1 miss-queue serialization)
__device__ __forceinline__ uint32_t ld_bypass(const uint32_t* p) {
    return __hip_atomic_load(p, __ATOMIC_RELAXED, __HIP_MEMORY_SCOPE_AGENT);
}

// ---------- pass 1: tables fp32 [16][2^19][2] -> packed fp16x2 [16][2^19] in ws
__global__ __launch_bounds__(256) void convert_kernel(
    const f2_t* __restrict__ tables, uint32_t* __restrict__ out, int total)
{
    int i = blockIdx.x * 256 + threadIdx.x;
    if (i >= total) return;
    f2_t v = __builtin_nontemporal_load(&tables[i]);
    __half2 h = __floats2half2_rn(v.x, v.y);   // .x in low 16 bits
    union { __half2 h2; uint32_t u; } cvt; cvt.h2 = h;
    __builtin_nontemporal_store(cvt.u, &out[i]);
}

// ---------- corner indices + trilinear weights for one level (order = _OFFSETS)
__device__ __forceinline__ void make_corners(
    float px, float py, float pz, float res, uint32_t* idx, float* w)
{
    float sx = ((px + 1.0f) * 0.5f) * res;
    float sy = ((py + 1.0f) * 0.5f) * res;
    float sz = ((pz + 1.0f) * 0.5f) * res;

    float fx = floorf(sx), fy = floorf(sy), fz = floorf(sz);
    float rx = sx - fx, ry = sy - fy, rz = sz - fz;

    float x0f = fminf(fmaxf(fx, 0.f), res), x1f = fminf(fmaxf(fx + 1.f, 0.f), res);
    float y0f = fminf(fmaxf(fy, 0.f), res), y1f = fminf(fmaxf(fy + 1.f, 0.f), res);
    float z0f = fminf(fmaxf(fz, 0.f), res), z1f = fminf(fmaxf(fz + 1.f, 0.f), res);

    uint32_t x0 = (uint32_t)x0f, x1 = (uint32_t)x1f;
    uint32_t hy0 = (uint32_t)y0f * 2654435761u, hy1 = (uint32_t)y1f * 2654435761u;
    uint32_t hz0 = (uint32_t)z0f * 805459861u,  hz1 = (uint32_t)z1f * 805459861u;

    float wx0 = 1.f - rx, wx1 = rx;
    float wy0 = 1.f - ry, wy1 = ry;
    float wz0 = 1.f - rz, wz1 = rz;

    idx[0] = (x0 ^ hy0 ^ hz0) & HMASK; w[0] = (wx0 * wy0) * wz0;
    idx[1] = (x0 ^ hy0 ^ hz1) & HMASK; w[1] = (wx0 * wy0) * wz1;
    idx[2] = (x0 ^ hy1 ^ hz0) & HMASK; w[2] = (wx0 * wy1) * wz0;
    idx[3] = (x0 ^ hy1 ^ hz1) & HMASK; w[3] = (wx0 * wy1) * wz1;
    idx[4] = (x1 ^ hy0 ^ hz0) & HMASK; w[4] = (wx1 * wy0) * wz0;
    idx[5] = (x1 ^ hy0 ^ hz1) & HMASK; w[5] = (wx1 * wy0) * wz1;
    idx[6] = (x1 ^ hy1 ^ hz0) & HMASK; w[6] = (wx1 * wy1) * wz0;
    idx[7] = (x1 ^ hy1 ^ hz1) & HMASK; w[7] = (wx1 * wy1) * wz1;
}

// ---------- pass 2: one thread = one point x one level-PAIR.
// blockIdx & 7 -> pair -> round-robin pins each pair's 2x2MiB tables to one XCD L2.
// All 16 gathers issued back-to-back (L1-bypass) before any blend: max MLP.
__global__ __launch_bounds__(256) void hashenc16_kernel(
    const float* __restrict__ pos, const uint32_t* __restrict__ tbl16,
    float* __restrict__ out, int n_points, ResArr ra)
{
    int b = blockIdx.x;
    int pair = b & 7;
    int point = (b >> 3) * 256 + threadIdx.x;
    if (point >= n_points) return;

    float res0, res1;
    switch (pair) {
        case 0: res0 = ra.r[0];  res1 = ra.r[1];  break;
        case 1: res0 = ra.r[2];  res1 = ra.r[3];  break;
        case 2: res0 = ra.r[4];  res1 = ra.r[5];  break;
        case 3: res0 = ra.r[6];  res1 = ra.r[7];  break;
        case 4: res0 = ra.r[8];  res1 = ra.r[9];  break;
        case 5: res0 = ra.r[10]; res1 = ra.r[11]; break;
        case 6: res0 = ra.r[12]; res1 = ra.r[13]; break;
        default: res0 = ra.r[14]; res1 = ra.r[15]; break;
    }

    const float* pp = pos + (size_t)point * 3;
    float px = __builtin_nontemporal_load(pp + 0);
    float py = __builtin_nontemporal_load(pp + 1);
    float pz = __builtin_nontemporal_load(pp + 2);

    const uint32_t* tblA = tbl16 + (size_t)(2 * pair)     * HASH_SIZE;
    const uint32_t* tblB = tbl16 + (size_t)(2 * pair + 1) * HASH_SIZE;

    uint32_t idxA[8], idxB[8];
    float wA[8], wB[8];
    make_corners(px, py, pz, res0, idxA, wA);
    make_corners(px, py, pz, res1, idxB, wB);

    uint32_t g[16];
    #pragma unroll
    for (int i = 0; i < 8; ++i) g[i]     = ld_bypass(tblA + idxA[i]);
    #pragma unroll
    for (int i = 0; i < 8; ++i) g[8 + i] = ld_bypass(tblB + idxB[i]);

    float a0 = 0.f, a1 = 0.f, b0 = 0.f, b1 = 0.f;
    #pragma unroll
    for (int i = 0; i < 8; ++i) {
        union { uint32_t u; __half2 h2; } c; c.u = g[i];
        float2 f = __half22float2(c.h2);
        a0 += wA[i] * f.x; a1 += wA[i] * f.y;
    }
    #pragma unroll
    for (int i = 0; i < 8; ++i) {
        union { uint32_t u; __half2 h2; } c; c.u = g[8 + i];
        float2 f = __half22float2(c.h2);
        b0 += wB[i] * f.x; b1 += wB[i] * f.y;
    }

    f4_t v = {a0, a1, b0, b1};
    f4_t* dst = reinterpret_cast<f4_t*>(out + (size_t)point * 32 + (size_t)pair * 4);
    __builtin_nontemporal_store(v, dst);
}

// ---------- fallback (ws too small): direct-fp32 kernel
__global__ __launch_bounds__(256) void hashenc_fp32_kernel(
    const float* __restrict__ pos, const float* __restrict__ tables,
    float* __restrict__ out, int n_points, ResArr res_arr)
{
    int tid = blockIdx.x * 256 + threadIdx.x;
    if (tid >= n_points * NUM_LEVELS) return;
    int level = tid & (NUM_LEVELS - 1);
    int point = tid >> 4;

    float px = pos[(size_t)point * 3 + 0];
    float py = pos[(size_t)point * 3 + 1];
    float pz = pos[(size_t)point * 3 + 2];
    float res = res_arr.r[level];

    uint32_t idx[8]; float w[8];
    make_corners(px, py, pz, res, idx, w);
    const float2* tbl = reinterpret_cast<const float2*>(tables) + (size_t)level * HASH_SIZE;
    float acc0 = 0.f, acc1 = 0.f;
    #pragma unroll
    for (int i = 0; i < 8; ++i) {
        float2 f = tbl[idx[i]];
        acc0 += w[i] * f.x; acc1 += w[i] * f.y;
    }
    union { float acc[2]; double d; } u;
    u.acc[0] = acc0; u.acc[1] = acc1;
    __builtin_nontemporal_store(u.d, reinterpret_cast<double*>(out) + ((size_t)point * 16 + level));
}

extern "C" void kernel_launch(void* const* d_in, const int* in_sizes, int n_in,
                              void* d_out, int out_size, void* d_ws, size_t ws_size,
                              hipStream_t stream) {
    const float* pos    = (const float*)d_in[0];
    const float* tables = (const float*)d_in[1];
    float* out = (float*)d_out;
    int n_points = in_sizes[0] / 3;

    // Replicate numpy exactly: RESOLUTIONS[i] = int(floor(16 * exp((i*log(32))/15)))
    ResArr ra;
    const double log32 = log(32.0);
    for (int i = 0; i < NUM_LEVELS; ++i)
        ra.r[i] = (float)(int)floor(16.0 * exp(((double)i * log32) / 15.0));

    const size_t need_ws = (size_t)NUM_LEVELS * HASH_SIZE * sizeof(uint32_t); // 32 MiB
    if (ws_size >= need_ws) {
        uint32_t* tbl16 = (uint32_t*)d_ws;
        int total = NUM_LEVELS * (int)HASH_SIZE;
        convert_kernel<<<(total + 255) / 256, 256, 0, stream>>>(
            (const f2_t*)tables, tbl16, total);
        int chunks = (n_points + 255) / 256;
        hashenc16_kernel<<<chunks * 8, 256, 0, stream>>>(pos, tbl16, out, n_points, ra);
    } else {
        long long total = (long long)n_points * NUM_LEVELS;
        hashenc_fp32_kernel<<<(int)((total + 255) / 256), 256, 0, stream>>>(
            pos, tables, out, n_points, ra);
    }
}

// Round 6
// 953.197 us; speedup vs baseline: 1.3748x; 1.3748x over previous
//
#include <hip/hip_runtime.h>
#include <hip/hip_fp16.h>
#include <stdint.h>
#include <cmath>

static constexpr int NUM_LEVELS = 16;
static constexpr uint32_t HASH_SIZE = 1u << 19;
static constexpr uint32_t HMASK = HASH_SIZE - 1u;
static constexpr int NB = 32;                     // bucket grid per axis
static constexpr int NBUCKETS = NB * NB * NB;     // 32768

typedef float f2_t __attribute__((ext_vector_type(2)));
typedef float f4_t __attribute__((ext_vector_type(4)));

struct ResArr { float r[NUM_LEVELS]; };

// ---------- tables fp32 [16][2^19][2] -> packed fp16x2 [16][2^19] in ws
__global__ __launch_bounds__(256) void convert_kernel(
    const f2_t* __restrict__ tables, uint32_t* __restrict__ out, int total)
{
    int i = blockIdx.x * 256 + threadIdx.x;
    if (i >= total) return;
    f2_t v = __builtin_nontemporal_load(&tables[i]);
    __half2 h = __floats2half2_rn(v.x, v.y);   // .x in low 16 bits
    union { __half2 h2; uint32_t u; } cvt; cvt.h2 = h;
    __builtin_nontemporal_store(cvt.u, &out[i]);
}

// ---------- corner indices + trilinear weights for one level (order = _OFFSETS)
__device__ __forceinline__ void make_corners(
    float px, float py, float pz, float res, uint32_t* idx, float* w)
{
    float sx = ((px + 1.0f) * 0.5f) * res;
    float sy = ((py + 1.0f) * 0.5f) * res;
    float sz = ((pz + 1.0f) * 0.5f) * res;

    float fx = floorf(sx), fy = floorf(sy), fz = floorf(sz);
    float rx = sx - fx, ry = sy - fy, rz = sz - fz;

    float x0f = fminf(fmaxf(fx, 0.f), res), x1f = fminf(fmaxf(fx + 1.f, 0.f), res);
    float y0f = fminf(fmaxf(fy, 0.f), res), y1f = fminf(fmaxf(fy + 1.f, 0.f), res);
    float z0f = fminf(fmaxf(fz, 0.f), res), z1f = fminf(fmaxf(fz + 1.f, 0.f), res);

    uint32_t x0 = (uint32_t)x0f, x1 = (uint32_t)x1f;
    uint32_t hy0 = (uint32_t)y0f * 2654435761u, hy1 = (uint32_t)y1f * 2654435761u;
    uint32_t hz0 = (uint32_t)z0f * 805459861u,  hz1 = (uint32_t)z1f * 805459861u;

    float wx0 = 1.f - rx, wx1 = rx;
    float wy0 = 1.f - ry, wy1 = ry;
    float wz0 = 1.f - rz, wz1 = rz;

    idx[0] = (x0 ^ hy0 ^ hz0) & HMASK; w[0] = (wx0 * wy0) * wz0;
    idx[1] = (x0 ^ hy0 ^ hz1) & HMASK; w[1] = (wx0 * wy0) * wz1;
    idx[2] = (x0 ^ hy1 ^ hz0) & HMASK; w[2] = (wx0 * wy1) * wz0;
    idx[3] = (x0 ^ hy1 ^ hz1) & HMASK; w[3] = (wx0 * wy1) * wz1;
    idx[4] = (x1 ^ hy0 ^ hz0) & HMASK; w[4] = (wx1 * wy0) * wz0;
    idx[5] = (x1 ^ hy0 ^ hz1) & HMASK; w[5] = (wx1 * wy0) * wz1;
    idx[6] = (x1 ^ hy1 ^ hz0) & HMASK; w[6] = (wx1 * wy1) * wz0;
    idx[7] = (x1 ^ hy1 ^ hz1) & HMASK; w[7] = (wx1 * wy1) * wz1;
}

// ---------- sort pass 1: bucket histogram
__global__ __launch_bounds__(256) void hist_kernel(
    const float* __restrict__ pos, uint32_t* __restrict__ counts, int n)
{
    int i = blockIdx.x * 256 + threadIdx.x;
    if (i >= n) return;
    float px = pos[(size_t)i * 3 + 0];
    float py = pos[(size_t)i * 3 + 1];
    float pz = pos[(size_t)i * 3 + 2];
    int kx = min(max((int)((px + 1.f) * 16.f), 0), NB - 1);
    int ky = min(max((int)((py + 1.f) * 16.f), 0), NB - 1);
    int kz = min(max((int)((pz + 1.f) * 16.f), 0), NB - 1);
    atomicAdd(&counts[(kx << 10) | (ky << 5) | kz], 1u);
}

// ---------- sort pass 2: exclusive prefix sum over 32768 counters (1 block)
__global__ __launch_bounds__(1024) void scan_kernel(
    const uint32_t* __restrict__ counts, uint32_t* __restrict__ offsets)
{
    __shared__ uint32_t lds[1024];
    int tid = threadIdx.x;
    uint32_t running = 0;
    for (int chunk = 0; chunk < NBUCKETS; chunk += 1024) {
        uint32_t v = counts[chunk + tid];
        lds[tid] = v;
        __syncthreads();
        #pragma unroll
        for (int off = 1; off < 1024; off <<= 1) {
            uint32_t t = (tid >= off) ? lds[tid - off] : 0u;
            __syncthreads();
            lds[tid] += t;
            __syncthreads();
        }
        offsets[chunk + tid] = running + lds[tid] - v;   // exclusive
        running += lds[1023];
        __syncthreads();
    }
}

// ---------- sort pass 3: scatter points to bucket slots
__global__ __launch_bounds__(256) void scatter_kernel(
    const float* __restrict__ pos, uint32_t* __restrict__ offs,
    float4* __restrict__ sorted, int n)
{
    int i = blockIdx.x * 256 + threadIdx.x;
    if (i >= n) return;
    float px = pos[(size_t)i * 3 + 0];
    float py = pos[(size_t)i * 3 + 1];
    float pz = pos[(size_t)i * 3 + 2];
    int kx = min(max((int)((px + 1.f) * 16.f), 0), NB - 1);
    int ky = min(max((int)((py + 1.f) * 16.f), 0), NB - 1);
    int kz = min(max((int)((pz + 1.f) * 16.f), 0), NB - 1);
    uint32_t slot = atomicAdd(&offs[(kx << 10) | (ky << 5) | kz], 1u);
    sorted[slot] = make_float4(px, py, pz, __uint_as_float((uint32_t)i));
}

// ---------- main: one thread = one SORTED point, all 16 levels.
// Spatial adjacency within wave -> lane-merged gathers + L1 reuse.
// Writes the point's full 128B output row (2 whole lines, no partial-line RMW).
__global__ __launch_bounds__(256) void hashenc_sorted_kernel(
    const float4* __restrict__ sorted, const uint32_t* __restrict__ tbl16,
    float* __restrict__ out, int n_points, ResArr ra)
{
    int gid = blockIdx.x * 256 + threadIdx.x;
    if (gid >= n_points) return;
    float4 t = sorted[gid];
    float px = t.x, py = t.y, pz = t.z;
    uint32_t orig = __float_as_uint(t.w);

    f4_t r[8];
    #pragma unroll
    for (int p = 0; p < 8; ++p) {
        const uint32_t* tA = tbl16 + (size_t)(2 * p)     * HASH_SIZE;
        const uint32_t* tB = tbl16 + (size_t)(2 * p + 1) * HASH_SIZE;
        uint32_t idxA[8], idxB[8];
        float wA[8], wB[8];
        make_corners(px, py, pz, ra.r[2 * p],     idxA, wA);
        make_corners(px, py, pz, ra.r[2 * p + 1], idxB, wB);

        uint32_t g[16];
        #pragma unroll
        for (int i = 0; i < 8; ++i) g[i]     = tA[idxA[i]];
        #pragma unroll
        for (int i = 0; i < 8; ++i) g[8 + i] = tB[idxB[i]];

        float a0 = 0.f, a1 = 0.f, b0 = 0.f, b1 = 0.f;
        #pragma unroll
        for (int i = 0; i < 8; ++i) {
            union { uint32_t u; __half2 h2; } c; c.u = g[i];
            float2 f = __half22float2(c.h2);
            a0 += wA[i] * f.x; a1 += wA[i] * f.y;
        }
        #pragma unroll
        for (int i = 0; i < 8; ++i) {
            union { uint32_t u; __half2 h2; } c; c.u = g[8 + i];
            float2 f = __half22float2(c.h2);
            b0 += wB[i] * f.x; b1 += wB[i] * f.y;
        }
        r[p] = (f4_t){a0, a1, b0, b1};
    }

    f4_t* dst = reinterpret_cast<f4_t*>(out + (size_t)orig * 32);
    #pragma unroll
    for (int k = 0; k < 8; ++k) __builtin_nontemporal_store(r[k], dst + k);
}

// ---------- fallback A (ws >= 32MB only): round-4 pair-split kernel
__global__ __launch_bounds__(256) void hashenc16_kernel(
    const float* __restrict__ pos, const uint32_t* __restrict__ tbl16,
    float* __restrict__ out, int n_points, ResArr ra)
{
    int b = blockIdx.x;
    int pair = b & 7;
    int point = (b >> 3) * 256 + threadIdx.x;
    if (point >= n_points) return;
    float res0 = ra.r[2 * pair], res1 = ra.r[2 * pair + 1];

    const float* pp = pos + (size_t)point * 3;
    float px = pp[0], py = pp[1], pz = pp[2];
    const uint32_t* tblA = tbl16 + (size_t)(2 * pair)     * HASH_SIZE;
    const uint32_t* tblB = tbl16 + (size_t)(2 * pair + 1) * HASH_SIZE;

    uint32_t idxA[8], idxB[8]; float wA[8], wB[8];
    make_corners(px, py, pz, res0, idxA, wA);
    make_corners(px, py, pz, res1, idxB, wB);
    uint32_t g[16];
    #pragma unroll
    for (int i = 0; i < 8; ++i) g[i]     = tblA[idxA[i]];
    #pragma unroll
    for (int i = 0; i < 8; ++i) g[8 + i] = tblB[idxB[i]];
    float a0 = 0.f, a1 = 0.f, b0 = 0.f, b1 = 0.f;
    #pragma unroll
    for (int i = 0; i < 8; ++i) {
        union { uint32_t u; __half2 h2; } c; c.u = g[i];
        float2 f = __half22float2(c.h2);
        a0 += wA[i] * f.x; a1 += wA[i] * f.y;
    }
    #pragma unroll
    for (int i = 0; i < 8; ++i) {
        union { uint32_t u; __half2 h2; } c; c.u = g[8 + i];
        float2 f = __half22float2(c.h2);
        b0 += wB[i] * f.x; b1 += wB[i] * f.y;
    }
    f4_t v = {a0, a1, b0, b1};
    __builtin_nontemporal_store(v,
        reinterpret_cast<f4_t*>(out + (size_t)point * 32 + (size_t)pair * 4));
}

// ---------- fallback B: direct fp32
__global__ __launch_bounds__(256) void hashenc_fp32_kernel(
    const float* __restrict__ pos, const float* __restrict__ tables,
    float* __restrict__ out, int n_points, ResArr res_arr)
{
    int tid = blockIdx.x * 256 + threadIdx.x;
    if (tid >= n_points * NUM_LEVELS) return;
    int level = tid & (NUM_LEVELS - 1);
    int point = tid >> 4;
    float px = pos[(size_t)point * 3 + 0];
    float py = pos[(size_t)point * 3 + 1];
    float pz = pos[(size_t)point * 3 + 2];
    uint32_t idx[8]; float w[8];
    make_corners(px, py, pz, res_arr.r[level], idx, w);
    const float2* tbl = reinterpret_cast<const float2*>(tables) + (size_t)level * HASH_SIZE;
    float acc0 = 0.f, acc1 = 0.f;
    #pragma unroll
    for (int i = 0; i < 8; ++i) {
        float2 f = tbl[idx[i]];
        acc0 += w[i] * f.x; acc1 += w[i] * f.y;
    }
    union { float acc[2]; double d; } u;
    u.acc[0] = acc0; u.acc[1] = acc1;
    __builtin_nontemporal_store(u.d, reinterpret_cast<double*>(out) + ((size_t)point * 16 + level));
}

extern "C" void kernel_launch(void* const* d_in, const int* in_sizes, int n_in,
                              void* d_out, int out_size, void* d_ws, size_t ws_size,
                              hipStream_t stream) {
    const float* pos    = (const float*)d_in[0];
    const float* tables = (const float*)d_in[1];
    float* out = (float*)d_out;
    int n_points = in_sizes[0] / 3;

    // Replicate numpy exactly: RESOLUTIONS[i] = int(floor(16 * exp((i*log(32))/15)))
    ResArr ra;
    const double log32 = log(32.0);
    for (int i = 0; i < NUM_LEVELS; ++i)
        ra.r[i] = (float)(int)floor(16.0 * exp(((double)i * log32) / 15.0));

    const size_t tbl_bytes    = (size_t)NUM_LEVELS * HASH_SIZE * sizeof(uint32_t); // 32 MiB
    const size_t sorted_bytes = (size_t)n_points * sizeof(float4);                 // 32 MiB
    const size_t cnt_bytes    = (size_t)NBUCKETS * sizeof(uint32_t);               // 128 KiB
    const size_t need_sorted  = tbl_bytes + sorted_bytes + 2 * cnt_bytes;

    int pblocks = (n_points + 255) / 256;
    int ttotal  = NUM_LEVELS * (int)HASH_SIZE;

    if (ws_size >= need_sorted) {
        char* ws = (char*)d_ws;
        uint32_t* tbl16   = (uint32_t*)(ws);
        float4*   sorted  = (float4*)(ws + tbl_bytes);
        uint32_t* offsets = (uint32_t*)(ws + tbl_bytes + sorted_bytes);
        uint32_t* counts  = (uint32_t*)(ws + tbl_bytes + sorted_bytes + cnt_bytes);

        convert_kernel<<<(ttotal + 255) / 256, 256, 0, stream>>>(
            (const f2_t*)tables, tbl16, ttotal);
        hipMemsetAsync(counts, 0, cnt_bytes, stream);
        hist_kernel<<<pblocks, 256, 0, stream>>>(pos, counts, n_points);
        scan_kernel<<<1, 1024, 0, stream>>>(counts, offsets);
        scatter_kernel<<<pblocks, 256, 0, stream>>>(pos, offsets, sorted, n_points);
        hashenc_sorted_kernel<<<pblocks, 256, 0, stream>>>(
            sorted, tbl16, out, n_points, ra);
    } else if (ws_size >= tbl_bytes) {
        uint32_t* tbl16 = (uint32_t*)d_ws;
        convert_kernel<<<(ttotal + 255) / 256, 256, 0, stream>>>(
            (const f2_t*)tables, tbl16, ttotal);
        hashenc16_kernel<<<pblocks * 8, 256, 0, stream>>>(pos, tbl16, out, n_points, ra);
    } else {
        long long total = (long long)n_points * NUM_LEVELS;
        hashenc_fp32_kernel<<<(int)((total + 255) / 256), 256, 0, stream>>>(
            pos, tables, out, n_points, ra);
    }
}

// Round 7
// 789.826 us; speedup vs baseline: 1.6591x; 1.2068x over previous
//
#include <hip/hip_runtime.h>
#include <hip/hip_fp16.h>
#include <stdint.h>
#include <cmath>

static constexpr int NUM_LEVELS = 16;
static constexpr uint32_t HASH_SIZE = 1u << 19;
static constexpr uint32_t HMASK = HASH_SIZE - 1u;
static constexpr int NB = 32;                     // bucket grid per axis
static constexpr int NBUCKETS = NB * NB * NB;     // 32768

typedef float f2_t __attribute__((ext_vector_type(2)));
typedef float f4_t __attribute__((ext_vector_type(4)));

struct ResArr { float r[NUM_LEVELS]; };

// ---------- tables fp32 [16][2^19][2] -> packed fp16x2 [16][2^19] in ws
__global__ __launch_bounds__(256) void convert_kernel(
    const f2_t* __restrict__ tables, uint32_t* __restrict__ out, int total)
{
    int i = blockIdx.x * 256 + threadIdx.x;
    if (i >= total) return;
    f2_t v = __builtin_nontemporal_load(&tables[i]);
    __half2 h = __floats2half2_rn(v.x, v.y);   // .x in low 16 bits
    union { __half2 h2; uint32_t u; } cvt; cvt.h2 = h;
    __builtin_nontemporal_store(cvt.u, &out[i]);
}

// ---------- corner indices + trilinear weights for one level (order = _OFFSETS)
__device__ __forceinline__ void make_corners(
    float px, float py, float pz, float res, uint32_t* idx, float* w)
{
    float sx = ((px + 1.0f) * 0.5f) * res;
    float sy = ((py + 1.0f) * 0.5f) * res;
    float sz = ((pz + 1.0f) * 0.5f) * res;

    float fx = floorf(sx), fy = floorf(sy), fz = floorf(sz);
    float rx = sx - fx, ry = sy - fy, rz = sz - fz;

    float x0f = fminf(fmaxf(fx, 0.f), res), x1f = fminf(fmaxf(fx + 1.f, 0.f), res);
    float y0f = fminf(fmaxf(fy, 0.f), res), y1f = fminf(fmaxf(fy + 1.f, 0.f), res);
    float z0f = fminf(fmaxf(fz, 0.f), res), z1f = fminf(fmaxf(fz + 1.f, 0.f), res);

    uint32_t x0 = (uint32_t)x0f, x1 = (uint32_t)x1f;
    uint32_t hy0 = (uint32_t)y0f * 2654435761u, hy1 = (uint32_t)y1f * 2654435761u;
    uint32_t hz0 = (uint32_t)z0f * 805459861u,  hz1 = (uint32_t)z1f * 805459861u;

    float wx0 = 1.f - rx, wx1 = rx;
    float wy0 = 1.f - ry, wy1 = ry;
    float wz0 = 1.f - rz, wz1 = rz;

    idx[0] = (x0 ^ hy0 ^ hz0) & HMASK; w[0] = (wx0 * wy0) * wz0;
    idx[1] = (x0 ^ hy0 ^ hz1) & HMASK; w[1] = (wx0 * wy0) * wz1;
    idx[2] = (x0 ^ hy1 ^ hz0) & HMASK; w[2] = (wx0 * wy1) * wz0;
    idx[3] = (x0 ^ hy1 ^ hz1) & HMASK; w[3] = (wx0 * wy1) * wz1;
    idx[4] = (x1 ^ hy0 ^ hz0) & HMASK; w[4] = (wx1 * wy0) * wz0;
    idx[5] = (x1 ^ hy0 ^ hz1) & HMASK; w[5] = (wx1 * wy0) * wz1;
    idx[6] = (x1 ^ hy1 ^ hz0) & HMASK; w[6] = (wx1 * wy1) * wz0;
    idx[7] = (x1 ^ hy1 ^ hz1) & HMASK; w[7] = (wx1 * wy1) * wz1;
}

// ---------- sort pass 1: bucket histogram
__global__ __launch_bounds__(256) void hist_kernel(
    const float* __restrict__ pos, uint32_t* __restrict__ counts, int n)
{
    int i = blockIdx.x * 256 + threadIdx.x;
    if (i >= n) return;
    float px = pos[(size_t)i * 3 + 0];
    float py = pos[(size_t)i * 3 + 1];
    float pz = pos[(size_t)i * 3 + 2];
    int kx = min(max((int)((px + 1.f) * 16.f), 0), NB - 1);
    int ky = min(max((int)((py + 1.f) * 16.f), 0), NB - 1);
    int kz = min(max((int)((pz + 1.f) * 16.f), 0), NB - 1);
    atomicAdd(&counts[(kx << 10) | (ky << 5) | kz], 1u);
}

// ---------- sort pass 2: exclusive prefix sum over 32768 counters (1 block)
__global__ __launch_bounds__(1024) void scan_kernel(
    const uint32_t* __restrict__ counts, uint32_t* __restrict__ offsets)
{
    __shared__ uint32_t lds[1024];
    int tid = threadIdx.x;
    uint32_t running = 0;
    for (int chunk = 0; chunk < NBUCKETS; chunk += 1024) {
        uint32_t v = counts[chunk + tid];
        lds[tid] = v;
        __syncthreads();
        #pragma unroll
        for (int off = 1; off < 1024; off <<= 1) {
            uint32_t t = (tid >= off) ? lds[tid - off] : 0u;
            __syncthreads();
            lds[tid] += t;
            __syncthreads();
        }
        offsets[chunk + tid] = running + lds[tid] - v;   // exclusive
        running += lds[1023];
        __syncthreads();
    }
}

// ---------- sort pass 3: scatter points to bucket slots (cached stores: L2 absorbs)
__global__ __launch_bounds__(256) void scatter_kernel(
    const float* __restrict__ pos, uint32_t* __restrict__ offs,
    float4* __restrict__ sorted, int n)
{
    int i = blockIdx.x * 256 + threadIdx.x;
    if (i >= n) return;
    float px = pos[(size_t)i * 3 + 0];
    float py = pos[(size_t)i * 3 + 1];
    float pz = pos[(size_t)i * 3 + 2];
    int kx = min(max((int)((px + 1.f) * 16.f), 0), NB - 1);
    int ky = min(max((int)((py + 1.f) * 16.f), 0), NB - 1);
    int kz = min(max((int)((pz + 1.f) * 16.f), 0), NB - 1);
    uint32_t slot = atomicAdd(&offs[(kx << 10) | (ky << 5) | kz], 1u);
    sorted[slot] = make_float4(px, py, pz, __uint_as_float((uint32_t)i));
}

// ---------- main: one thread = one SORTED point, all 16 levels.
// Chunked XCD swizzle: hardware assigns XCD = blockIdx%8 (round-robin), so
// sbid=(bid&7)*nchunk+(bid>>3) gives each XCD a CONTIGUOUS chunk of the sorted
// stream -> each spatial region lives in exactly one XCD's L2 -> table lines
// fetched from HBM ~once. Output: cached stores, full 128B row per thread.
__global__ __launch_bounds__(256) void hashenc_sorted_kernel(
    const float4* __restrict__ sorted, const uint32_t* __restrict__ tbl16,
    float* __restrict__ out, int n_points, int nchunk, ResArr ra)
{
    int bid = blockIdx.x;
    int sbid = (bid & 7) * nchunk + (bid >> 3);
    int gid = sbid * 256 + threadIdx.x;
    if (gid >= n_points) return;

    f4_t t = __builtin_nontemporal_load(
        reinterpret_cast<const f4_t*>(sorted) + gid);
    float px = t.x, py = t.y, pz = t.z;
    uint32_t orig = __float_as_uint(t.w);

    f4_t r[8];
    #pragma unroll
    for (int p = 0; p < 8; ++p) {
        const uint32_t* tA = tbl16 + (size_t)(2 * p)     * HASH_SIZE;
        const uint32_t* tB = tbl16 + (size_t)(2 * p + 1) * HASH_SIZE;
        uint32_t idxA[8], idxB[8];
        float wA[8], wB[8];
        make_corners(px, py, pz, ra.r[2 * p],     idxA, wA);
        make_corners(px, py, pz, ra.r[2 * p + 1], idxB, wB);

        uint32_t g[16];
        #pragma unroll
        for (int i = 0; i < 8; ++i) g[i]     = tA[idxA[i]];
        #pragma unroll
        for (int i = 0; i < 8; ++i) g[8 + i] = tB[idxB[i]];

        float a0 = 0.f, a1 = 0.f, b0 = 0.f, b1 = 0.f;
        #pragma unroll
        for (int i = 0; i < 8; ++i) {
            union { uint32_t u; __half2 h2; } c; c.u = g[i];
            float2 f = __half22float2(c.h2);
            a0 += wA[i] * f.x; a1 += wA[i] * f.y;
        }
        #pragma unroll
        for (int i = 0; i < 8; ++i) {
            union { uint32_t u; __half2 h2; } c; c.u = g[8 + i];
            float2 f = __half22float2(c.h2);
            b0 += wB[i] * f.x; b1 += wB[i] * f.y;
        }
        r[p] = (f4_t){a0, a1, b0, b1};
    }

    // cached stores: one thread fills two whole 64B lines -> clean write-back,
    // no RMW fetch, no nt partial-sector amplification
    f4_t* dst = reinterpret_cast<f4_t*>(out + (size_t)orig * 32);
    #pragma unroll
    for (int k = 0; k < 8; ++k) dst[k] = r[k];
}

// ---------- fallback A (ws >= 32MB only): pair-split kernel
__global__ __launch_bounds__(256) void hashenc16_kernel(
    const float* __restrict__ pos, const uint32_t* __restrict__ tbl16,
    float* __restrict__ out, int n_points, ResArr ra)
{
    int b = blockIdx.x;
    int pair = b & 7;
    int point = (b >> 3) * 256 + threadIdx.x;
    if (point >= n_points) return;
    float res0 = ra.r[2 * pair], res1 = ra.r[2 * pair + 1];

    const float* pp = pos + (size_t)point * 3;
    float px = pp[0], py = pp[1], pz = pp[2];
    const uint32_t* tblA = tbl16 + (size_t)(2 * pair)     * HASH_SIZE;
    const uint32_t* tblB = tbl16 + (size_t)(2 * pair + 1) * HASH_SIZE;

    uint32_t idxA[8], idxB[8]; float wA[8], wB[8];
    make_corners(px, py, pz, res0, idxA, wA);
    make_corners(px, py, pz, res1, idxB, wB);
    uint32_t g[16];
    #pragma unroll
    for (int i = 0; i < 8; ++i) g[i]     = tblA[idxA[i]];
    #pragma unroll
    for (int i = 0; i < 8; ++i) g[8 + i] = tblB[idxB[i]];
    float a0 = 0.f, a1 = 0.f, b0 = 0.f, b1 = 0.f;
    #pragma unroll
    for (int i = 0; i < 8; ++i) {
        union { uint32_t u; __half2 h2; } c; c.u = g[i];
        float2 f = __half22float2(c.h2);
        a0 += wA[i] * f.x; a1 += wA[i] * f.y;
    }
    #pragma unroll
    for (int i = 0; i < 8; ++i) {
        union { uint32_t u; __half2 h2; } c; c.u = g[8 + i];
        float2 f = __half22float2(c.h2);
        b0 += wB[i] * f.x; b1 += wB[i] * f.y;
    }
    f4_t v = {a0, a1, b0, b1};
    *reinterpret_cast<f4_t*>(out + (size_t)point * 32 + (size_t)pair * 4) = v;
}

// ---------- fallback B: direct fp32
__global__ __launch_bounds__(256) void hashenc_fp32_kernel(
    const float* __restrict__ pos, const float* __restrict__ tables,
    float* __restrict__ out, int n_points, ResArr res_arr)
{
    int tid = blockIdx.x * 256 + threadIdx.x;
    if (tid >= n_points * NUM_LEVELS) return;
    int level = tid & (NUM_LEVELS - 1);
    int point = tid >> 4;
    float px = pos[(size_t)point * 3 + 0];
    float py = pos[(size_t)point * 3 + 1];
    float pz = pos[(size_t)point * 3 + 2];
    uint32_t idx[8]; float w[8];
    make_corners(px, py, pz, res_arr.r[level], idx, w);
    const float2* tbl = reinterpret_cast<const float2*>(tables) + (size_t)level * HASH_SIZE;
    float acc0 = 0.f, acc1 = 0.f;
    #pragma unroll
    for (int i = 0; i < 8; ++i) {
        float2 f = tbl[idx[i]];
        acc0 += w[i] * f.x; acc1 += w[i] * f.y;
    }
    union { float acc[2]; double d; } u;
    u.acc[0] = acc0; u.acc[1] = acc1;
    __builtin_nontemporal_store(u.d, reinterpret_cast<double*>(out) + ((size_t)point * 16 + level));
}

extern "C" void kernel_launch(void* const* d_in, const int* in_sizes, int n_in,
                              void* d_out, int out_size, void* d_ws, size_t ws_size,
                              hipStream_t stream) {
    const float* pos    = (const float*)d_in[0];
    const float* tables = (const float*)d_in[1];
    float* out = (float*)d_out;
    int n_points = in_sizes[0] / 3;

    // Replicate numpy exactly: RESOLUTIONS[i] = int(floor(16 * exp((i*log(32))/15)))
    ResArr ra;
    const double log32 = log(32.0);
    for (int i = 0; i < NUM_LEVELS; ++i)
        ra.r[i] = (float)(int)floor(16.0 * exp(((double)i * log32) / 15.0));

    const size_t tbl_bytes    = (size_t)NUM_LEVELS * HASH_SIZE * sizeof(uint32_t); // 32 MiB
    const size_t sorted_bytes = (size_t)n_points * sizeof(float4);                 // 32 MiB
    const size_t cnt_bytes    = (size_t)NBUCKETS * sizeof(uint32_t);               // 128 KiB
    const size_t need_sorted  = tbl_bytes + sorted_bytes + 2 * cnt_bytes;

    int pblocks = (n_points + 255) / 256;
    int ttotal  = NUM_LEVELS * (int)HASH_SIZE;

    if (ws_size >= need_sorted) {
        char* ws = (char*)d_ws;
        uint32_t* tbl16   = (uint32_t*)(ws);
        float4*   sorted  = (float4*)(ws + tbl_bytes);
        uint32_t* offsets = (uint32_t*)(ws + tbl_bytes + sorted_bytes);
        uint32_t* counts  = (uint32_t*)(ws + tbl_bytes + sorted_bytes + cnt_bytes);

        convert_kernel<<<(ttotal + 255) / 256, 256, 0, stream>>>(
            (const f2_t*)tables, tbl16, ttotal);
        hipMemsetAsync(counts, 0, cnt_bytes, stream);
        hist_kernel<<<pblocks, 256, 0, stream>>>(pos, counts, n_points);
        scan_kernel<<<1, 1024, 0, stream>>>(counts, offsets);
        scatter_kernel<<<pblocks, 256, 0, stream>>>(pos, offsets, sorted, n_points);

        int nchunk = (pblocks + 7) / 8;          // blocks per XCD chunk
        hashenc_sorted_kernel<<<nchunk * 8, 256, 0, stream>>>(
            sorted, tbl16, out, n_points, nchunk, ra);
    } else if (ws_size >= tbl_bytes) {
        uint32_t* tbl16 = (uint32_t*)d_ws;
        convert_kernel<<<(ttotal + 255) / 256, 256, 0, stream>>>(
            (const f2_t*)tables, tbl16, ttotal);
        hashenc16_kernel<<<pblocks * 8, 256, 0, stream>>>(pos, tbl16, out, n_points, ra);
    } else {
        long long total = (long long)n_points * NUM_LEVELS;
        hashenc_fp32_kernel<<<(int)((total + 255) / 256), 256, 0, stream>>>(
            pos, tables, out, n_points, ra);
    }
}

// Round 8
// 630.303 us; speedup vs baseline: 2.0790x; 1.2531x over previous
//
#include <hip/hip_runtime.h>
#include <hip/hip_fp16.h>
#include <stdint.h>
#include <cmath>

static constexpr int NUM_LEVELS = 16;
static constexpr uint32_t HASH_SIZE = 1u << 19;
static constexpr uint32_t HMASK = HASH_SIZE - 1u;
static constexpr int NB = 32;                     // bucket grid per axis
static constexpr int NBUCKETS = NB * NB * NB;     // 32768
static constexpr int CAP = 128;                   // padded slots/bucket (avg fill ~64)
static constexpr int OVCAP = 4096;                // overflow list capacity

typedef float    f2_t __attribute__((ext_vector_type(2)));
typedef float    f4_t __attribute__((ext_vector_type(4)));
typedef uint32_t u2_t __attribute__((ext_vector_type(2)));

struct ResArr { float r[NUM_LEVELS]; };

// ---------- corner indices + trilinear weights for one level (order = _OFFSETS)
__device__ __forceinline__ void make_corners(
    float px, float py, float pz, float res, uint32_t* idx, float* w)
{
    float sx = ((px + 1.0f) * 0.5f) * res;
    float sy = ((py + 1.0f) * 0.5f) * res;
    float sz = ((pz + 1.0f) * 0.5f) * res;

    float fx = floorf(sx), fy = floorf(sy), fz = floorf(sz);
    float rx = sx - fx, ry = sy - fy, rz = sz - fz;

    float x0f = fminf(fmaxf(fx, 0.f), res), x1f = fminf(fmaxf(fx + 1.f, 0.f), res);
    float y0f = fminf(fmaxf(fy, 0.f), res), y1f = fminf(fmaxf(fy + 1.f, 0.f), res);
    float z0f = fminf(fmaxf(fz, 0.f), res), z1f = fminf(fmaxf(fz + 1.f, 0.f), res);

    uint32_t x0 = (uint32_t)x0f, x1 = (uint32_t)x1f;
    uint32_t hy0 = (uint32_t)y0f * 2654435761u, hy1 = (uint32_t)y1f * 2654435761u;
    uint32_t hz0 = (uint32_t)z0f * 805459861u,  hz1 = (uint32_t)z1f * 805459861u;

    float wx0 = 1.f - rx, wx1 = rx;
    float wy0 = 1.f - ry, wy1 = ry;
    float wz0 = 1.f - rz, wz1 = rz;

    idx[0] = (x0 ^ hy0 ^ hz0) & HMASK; w[0] = (wx0 * wy0) * wz0;
    idx[1] = (x0 ^ hy0 ^ hz1) & HMASK; w[1] = (wx0 * wy0) * wz1;
    idx[2] = (x0 ^ hy1 ^ hz0) & HMASK; w[2] = (wx0 * wy1) * wz0;
    idx[3] = (x0 ^ hy1 ^ hz1) & HMASK; w[3] = (wx0 * wy1) * wz1;
    idx[4] = (x1 ^ hy0 ^ hz0) & HMASK; w[4] = (wx1 * wy0) * wz0;
    idx[5] = (x1 ^ hy0 ^ hz1) & HMASK; w[5] = (wx1 * wy0) * wz1;
    idx[6] = (x1 ^ hy1 ^ hz0) & HMASK; w[6] = (wx1 * wy1) * wz0;
    idx[7] = (x1 ^ hy1 ^ hz1) & HMASK; w[7] = (wx1 * wy1) * wz1;
}

// ---------- all 16 levels for one point from packed fp16 tables
__device__ __forceinline__ void enc_all16(
    float px, float py, float pz, const uint32_t* __restrict__ tbl16,
    const ResArr& ra, f4_t r[8])
{
    #pragma unroll
    for (int p = 0; p < 8; ++p) {
        const uint32_t* tA = tbl16 + (size_t)(2 * p)     * HASH_SIZE;
        const uint32_t* tB = tbl16 + (size_t)(2 * p + 1) * HASH_SIZE;
        uint32_t idxA[8], idxB[8];
        float wA[8], wB[8];
        make_corners(px, py, pz, ra.r[2 * p],     idxA, wA);
        make_corners(px, py, pz, ra.r[2 * p + 1], idxB, wB);

        uint32_t g[16];
        #pragma unroll
        for (int i = 0; i < 8; ++i) g[i]     = tA[idxA[i]];
        #pragma unroll
        for (int i = 0; i < 8; ++i) g[8 + i] = tB[idxB[i]];

        float a0 = 0.f, a1 = 0.f, b0 = 0.f, b1 = 0.f;
        #pragma unroll
        for (int i = 0; i < 8; ++i) {
            union { uint32_t u; __half2 h2; } c; c.u = g[i];
            float2 f = __half22float2(c.h2);
            a0 += wA[i] * f.x; a1 += wA[i] * f.y;
        }
        #pragma unroll
        for (int i = 0; i < 8; ++i) {
            union { uint32_t u; __half2 h2; } c; c.u = g[8 + i];
            float2 f = __half22float2(c.h2);
            b0 += wB[i] * f.x; b1 += wB[i] * f.y;
        }
        r[p] = (f4_t){a0, a1, b0, b1};
    }
}

// ---------- fused prep: blocks [0,conv_blocks) convert tables fp32->fp16x2;
// remaining blocks bucket-scatter points into padded slots (no hist/scan passes).
__global__ __launch_bounds__(256) void fused_prep_kernel(
    const f4_t* __restrict__ tables4, const float* __restrict__ pos,
    uint32_t* __restrict__ tbl16, f4_t* __restrict__ padded,
    uint32_t* __restrict__ counts, uint32_t* __restrict__ ovcnt,
    f4_t* __restrict__ ovlist, int n_points, int conv_blocks)
{
    int b = blockIdx.x;
    if (b < conv_blocks) {
        // 2 table entries per thread: conv_blocks*256 == NUM_LEVELS*HASH_SIZE/2
        int i = b * 256 + threadIdx.x;
        f4_t v = __builtin_nontemporal_load(&tables4[i]);
        union { __half2 h2; uint32_t u; } a, c;
        a.h2 = __floats2half2_rn(v.x, v.y);
        c.h2 = __floats2half2_rn(v.z, v.w);
        u2_t o = {a.u, c.u};
        __builtin_nontemporal_store(o, reinterpret_cast<u2_t*>(tbl16) + i);
    } else {
        int i = (b - conv_blocks) * 256 + threadIdx.x;
        if (i >= n_points) return;
        float px = pos[(size_t)i * 3 + 0];
        float py = pos[(size_t)i * 3 + 1];
        float pz = pos[(size_t)i * 3 + 2];
        int kx = min(max((int)((px + 1.f) * 16.f), 0), NB - 1);
        int ky = min(max((int)((py + 1.f) * 16.f), 0), NB - 1);
        int kz = min(max((int)((pz + 1.f) * 16.f), 0), NB - 1);
        int bucket = (kx << 10) | (ky << 5) | kz;
        uint32_t rank = atomicAdd(&counts[bucket], 1u);
        f4_t rec = {px, py, pz, __uint_as_float((uint32_t)i)};
        if (rank < (uint32_t)CAP) {
            padded[(size_t)bucket * CAP + rank] = rec;
        } else {
            uint32_t ov = atomicAdd(ovcnt, 1u);   // ~never taken (Poisson(64) > 128)
            if (ov < (uint32_t)OVCAP) ovlist[ov] = rec;
        }
    }
}

// ---------- main: one thread = one padded slot (gid == bucket*CAP + slot).
// Chunked XCD swizzle keeps each spatial region on one XCD's L2.
__global__ __launch_bounds__(256) void hashenc_padded_kernel(
    const f4_t* __restrict__ padded, const uint32_t* __restrict__ counts,
    const uint32_t* __restrict__ tbl16, float* __restrict__ out,
    int nchunk, ResArr ra)
{
    int bid = blockIdx.x;
    int sbid = (bid & 7) * nchunk + (bid >> 3);
    int gid = sbid * 256 + threadIdx.x;
    int bucket = gid >> 7;                 // CAP == 128
    int slot   = gid & (CAP - 1);
    uint32_t cnt = counts[bucket];
    if (slot >= (int)min(cnt, (uint32_t)CAP)) return;

    f4_t t = padded[gid];
    float px = t.x, py = t.y, pz = t.z;
    uint32_t orig = __float_as_uint(t.w);

    f4_t r[8];
    enc_all16(px, py, pz, tbl16, ra, r);

    // cached stores: full 128B row -> clean line write-back, no RMW
    f4_t* dst = reinterpret_cast<f4_t*>(out + (size_t)orig * 32);
    #pragma unroll
    for (int k = 0; k < 8; ++k) dst[k] = r[k];
}

// ---------- overflow cleanup (empty in practice; guarantees correctness)
__global__ __launch_bounds__(256) void overflow_kernel(
    const f4_t* __restrict__ ovlist, const uint32_t* __restrict__ ovcnt,
    const uint32_t* __restrict__ tbl16, float* __restrict__ out, ResArr ra)
{
    uint32_t n = min(*ovcnt, (uint32_t)OVCAP);
    for (uint32_t i = threadIdx.x; i < n; i += 256) {
        f4_t t = ovlist[i];
        f4_t r[8];
        enc_all16(t.x, t.y, t.z, tbl16, ra, r);
        f4_t* dst = reinterpret_cast<f4_t*>(out + (size_t)__float_as_uint(t.w) * 32);
        #pragma unroll
        for (int k = 0; k < 8; ++k) dst[k] = r[k];
    }
}

// ================= fallback path (ws < padded need): round-7 3-pass sort =====
__global__ __launch_bounds__(256) void convert_kernel(
    const f2_t* __restrict__ tables, uint32_t* __restrict__ out, int total)
{
    int i = blockIdx.x * 256 + threadIdx.x;
    if (i >= total) return;
    f2_t v = __builtin_nontemporal_load(&tables[i]);
    __half2 h = __floats2half2_rn(v.x, v.y);
    union { __half2 h2; uint32_t u; } cvt; cvt.h2 = h;
    __builtin_nontemporal_store(cvt.u, &out[i]);
}

__global__ __launch_bounds__(256) void hist_kernel(
    const float* __restrict__ pos, uint32_t* __restrict__ counts, int n)
{
    int i = blockIdx.x * 256 + threadIdx.x;
    if (i >= n) return;
    int kx = min(max((int)((pos[(size_t)i*3+0] + 1.f) * 16.f), 0), NB - 1);
    int ky = min(max((int)((pos[(size_t)i*3+1] + 1.f) * 16.f), 0), NB - 1);
    int kz = min(max((int)((pos[(size_t)i*3+2] + 1.f) * 16.f), 0), NB - 1);
    atomicAdd(&counts[(kx << 10) | (ky << 5) | kz], 1u);
}

__global__ __launch_bounds__(1024) void scan_kernel(
    const uint32_t* __restrict__ counts, uint32_t* __restrict__ offsets)
{
    __shared__ uint32_t lds[1024];
    int tid = threadIdx.x;
    uint32_t running = 0;
    for (int chunk = 0; chunk < NBUCKETS; chunk += 1024) {
        uint32_t v = counts[chunk + tid];
        lds[tid] = v;
        __syncthreads();
        #pragma unroll
        for (int off = 1; off < 1024; off <<= 1) {
            uint32_t t = (tid >= off) ? lds[tid - off] : 0u;
            __syncthreads();
            lds[tid] += t;
            __syncthreads();
        }
        offsets[chunk + tid] = running + lds[tid] - v;
        running += lds[1023];
        __syncthreads();
    }
}

__global__ __launch_bounds__(256) void scatter_kernel(
    const float* __restrict__ pos, uint32_t* __restrict__ offs,
    float4* __restrict__ sorted, int n)
{
    int i = blockIdx.x * 256 + threadIdx.x;
    if (i >= n) return;
    float px = pos[(size_t)i*3+0], py = pos[(size_t)i*3+1], pz = pos[(size_t)i*3+2];
    int kx = min(max((int)((px + 1.f) * 16.f), 0), NB - 1);
    int ky = min(max((int)((py + 1.f) * 16.f), 0), NB - 1);
    int kz = min(max((int)((pz + 1.f) * 16.f), 0), NB - 1);
    uint32_t slot = atomicAdd(&offs[(kx << 10) | (ky << 5) | kz], 1u);
    sorted[slot] = make_float4(px, py, pz, __uint_as_float((uint32_t)i));
}

__global__ __launch_bounds__(256) void hashenc_sorted_kernel(
    const float4* __restrict__ sorted, const uint32_t* __restrict__ tbl16,
    float* __restrict__ out, int n_points, int nchunk, ResArr ra)
{
    int bid = blockIdx.x;
    int sbid = (bid & 7) * nchunk + (bid >> 3);
    int gid = sbid * 256 + threadIdx.x;
    if (gid >= n_points) return;
    f4_t t = __builtin_nontemporal_load(reinterpret_cast<const f4_t*>(sorted) + gid);
    f4_t r[8];
    enc_all16(t.x, t.y, t.z, tbl16, ra, r);
    f4_t* dst = reinterpret_cast<f4_t*>(out + (size_t)__float_as_uint(t.w) * 32);
    #pragma unroll
    for (int k = 0; k < 8; ++k) dst[k] = r[k];
}

__global__ __launch_bounds__(256) void hashenc_fp32_kernel(
    const float* __restrict__ pos, const float* __restrict__ tables,
    float* __restrict__ out, int n_points, ResArr res_arr)
{
    int tid = blockIdx.x * 256 + threadIdx.x;
    if (tid >= n_points * NUM_LEVELS) return;
    int level = tid & (NUM_LEVELS - 1);
    int point = tid >> 4;
    float px = pos[(size_t)point*3+0], py = pos[(size_t)point*3+1], pz = pos[(size_t)point*3+2];
    uint32_t idx[8]; float w[8];
    make_corners(px, py, pz, res_arr.r[level], idx, w);
    const float2* tbl = reinterpret_cast<const float2*>(tables) + (size_t)level * HASH_SIZE;
    float acc0 = 0.f, acc1 = 0.f;
    #pragma unroll
    for (int i = 0; i < 8; ++i) {
        float2 f = tbl[idx[i]];
        acc0 += w[i] * f.x; acc1 += w[i] * f.y;
    }
    union { float acc[2]; double d; } u;
    u.acc[0] = acc0; u.acc[1] = acc1;
    __builtin_nontemporal_store(u.d, reinterpret_cast<double*>(out) + ((size_t)point * 16 + level));
}

extern "C" void kernel_launch(void* const* d_in, const int* in_sizes, int n_in,
                              void* d_out, int out_size, void* d_ws, size_t ws_size,
                              hipStream_t stream) {
    const float* pos    = (const float*)d_in[0];
    const float* tables = (const float*)d_in[1];
    float* out = (float*)d_out;
    int n_points = in_sizes[0] / 3;

    // Replicate numpy exactly: RESOLUTIONS[i] = int(floor(16 * exp((i*log(32))/15)))
    ResArr ra;
    const double log32 = log(32.0);
    for (int i = 0; i < NUM_LEVELS; ++i)
        ra.r[i] = (float)(int)floor(16.0 * exp(((double)i * log32) / 15.0));

    const size_t tbl_bytes = (size_t)NUM_LEVELS * HASH_SIZE * sizeof(uint32_t);   // 32 MiB
    const size_t pad_bytes = (size_t)NBUCKETS * CAP * sizeof(f4_t);               // 64 MiB
    const size_t cnt_bytes = (size_t)NBUCKETS * sizeof(uint32_t);                 // 128 KiB
    const size_t ov_bytes  = 16 + (size_t)OVCAP * sizeof(f4_t);
    const size_t need_pad  = tbl_bytes + pad_bytes + cnt_bytes + ov_bytes;        // ~96.2 MiB

    const size_t sorted_bytes = (size_t)n_points * sizeof(float4);                // 32 MiB
    const size_t need_sorted  = tbl_bytes + sorted_bytes + 2 * cnt_bytes;         // ~64.3 MiB

    int pblocks = (n_points + 255) / 256;
    int ttotal  = NUM_LEVELS * (int)HASH_SIZE;

    if (ws_size >= need_pad) {
        char* ws = (char*)d_ws;
        uint32_t* tbl16  = (uint32_t*)(ws);
        f4_t*     padded = (f4_t*)(ws + tbl_bytes);
        uint32_t* counts = (uint32_t*)(ws + tbl_bytes + pad_bytes);
        uint32_t* ovcnt  = (uint32_t*)(ws + tbl_bytes + pad_bytes + cnt_bytes);
        f4_t*     ovlist = (f4_t*)(ws + tbl_bytes + pad_bytes + cnt_bytes + 16);

        hipMemsetAsync(counts, 0, cnt_bytes + 16, stream);
        int conv_blocks = ttotal / 2 / 256;                   // 16384
        fused_prep_kernel<<<conv_blocks + pblocks, 256, 0, stream>>>(
            (const f4_t*)tables, pos, tbl16, padded, counts, ovcnt, ovlist,
            n_points, conv_blocks);

        int nblocks = NBUCKETS * CAP / 256;                   // 16384
        int nchunk  = nblocks / 8;
        hashenc_padded_kernel<<<nblocks, 256, 0, stream>>>(
            padded, counts, tbl16, out, nchunk, ra);
        overflow_kernel<<<1, 256, 0, stream>>>(ovlist, ovcnt, tbl16, out, ra);
    } else if (ws_size >= need_sorted) {
        char* ws = (char*)d_ws;
        uint32_t* tbl16   = (uint32_t*)(ws);
        float4*   sorted  = (float4*)(ws + tbl_bytes);
        uint32_t* offsets = (uint32_t*)(ws + tbl_bytes + sorted_bytes);
        uint32_t* counts  = (uint32_t*)(ws + tbl_bytes + sorted_bytes + cnt_bytes);

        convert_kernel<<<(ttotal + 255) / 256, 256, 0, stream>>>(
            (const f2_t*)tables, tbl16, ttotal);
        hipMemsetAsync(counts, 0, cnt_bytes, stream);
        hist_kernel<<<pblocks, 256, 0, stream>>>(pos, counts, n_points);
        scan_kernel<<<1, 1024, 0, stream>>>(counts, offsets);
        scatter_kernel<<<pblocks, 256, 0, stream>>>(pos, offsets, sorted, n_points);
        int nchunk = (pblocks + 7) / 8;
        hashenc_sorted_kernel<<<nchunk * 8, 256, 0, stream>>>(
            sorted, tbl16, out, n_points, nchunk, ra);
    } else {
        long long total = (long long)n_points * NUM_LEVELS;
        hashenc_fp32_kernel<<<(int)((total + 255) / 256), 256, 0, stream>>>(
            pos, tables, out, n_points, ra);
    }
}